// Round 6
// baseline (47.507 us; speedup 1.0000x reference)
//
#include <hip/hip_runtime.h>
#include <math.h>

#define EPS 1e-8f

// Problem shape (fixed by setup_inputs)
constexpr int B = 8, H = 16, K = 2048, D = 128;
constexpr int BH = B * H;
constexpr int ROWS_PER_BLOCK = 32;               // fine-grained one-shot blocks
constexpr int CHUNKS = K / ROWS_PER_BLOCK;       // 64 blocks per (b,h)
constexpr int WAVES = 4;                         // 256 threads/block
constexpr int SLOTS = WAVES * 2;                 // 8 half-wave row-slots
constexpr int RPS = ROWS_PER_BLOCK / SLOTS;      // 4 rows per slot (contiguous)
constexpr size_t P_OFF = (size_t)BH * K * D;

typedef float f32x4 __attribute__((ext_vector_type(4)));

__global__ __launch_bounds__(256) void cosattn_kernel(
    const float* __restrict__ q,      // [BH, D]
    const float* __restrict__ key,    // [BH, K, D]
    const float* __restrict__ value,  // [BH, K, D]
    const int*   __restrict__ mask,   // [B, K]
    float* __restrict__ out)          // [BH*K*D] ++ [BH*K]
{
    const int tid  = threadIdx.x;
    const int lane = tid & 63;
    const int half = lane >> 5;       // which row-slot of the wave's pair
    const int l32  = lane & 31;       // lane within 32-lane row group
    const int wave = tid >> 6;
    const int slot = wave * 2 + half; // 0..7

    const int bh    = blockIdx.x >> 6;        // / CHUNKS
    const int chunk = blockIdx.x & (CHUNKS - 1);
    const int b     = bh / H;

    // This slot owns RPS contiguous rows.
    const int slotBase = chunk * ROWS_PER_BLOCK + slot * RPS;
    const size_t baseRow = (size_t)bh * K;

    // Mask bitmap: lanes 0..3 of each half-wave load this slot's masks.
    int mk = 0;
    if (l32 < RPS)
        mk = mask[b * K + slotBase + l32];
    const unsigned long long bal = __ballot(mk != 0);
    const unsigned bits = (unsigned)(bal >> (half * 32)) & 0xFu;

    // Per-lane query fragment (both halves identical).
    const f32x4 qv = *reinterpret_cast<const f32x4*>(q + (size_t)bh * D + l32 * 4);

    const float* kbase = key   + (baseRow + slotBase) * D + l32 * 4;
    const float* vbase = value + (baseRow + slotBase) * D + l32 * 4;
    float*       obase = out   + (baseRow + slotBase) * D + l32 * 4;

    // Issue all K loads, then all V loads (K first: compute can start at vmcnt(4)).
    f32x4 kv[RPS], vv[RPS];
    #pragma unroll
    for (int j = 0; j < RPS; ++j)
        kv[j] = ((bits >> j) & 1u) ? *reinterpret_cast<const f32x4*>(kbase + j * D)
                                   : (f32x4)(0.0f);
    #pragma unroll
    for (int j = 0; j < RPS; ++j)
        vv[j] = ((bits >> j) & 1u) ? *reinterpret_cast<const f32x4*>(vbase + j * D)
                                   : (f32x4)(0.0f);

    // q-norm reduction (5 shuffle steps, stays within each 32-lane half).
    float qsq = qv[0]*qv[0] + qv[1]*qv[1] + qv[2]*qv[2] + qv[3]*qv[3];
    #pragma unroll
    for (int s = 16; s >= 1; s >>= 1)
        qsq += __shfl_xor(qsq, s, 64);
    const float inv_qn = 1.0f / fmaxf(sqrtf(qsq), EPS);

    // Interleaved butterfly reductions for the 4 rows (needs only K data).
    float dot[RPS], ksq[RPS];
    #pragma unroll
    for (int j = 0; j < RPS; ++j) {
        dot[j] = qv[0]*kv[j][0] + qv[1]*kv[j][1] + qv[2]*kv[j][2] + qv[3]*kv[j][3];
        ksq[j] = kv[j][0]*kv[j][0] + kv[j][1]*kv[j][1] + kv[j][2]*kv[j][2] + kv[j][3]*kv[j][3];
    }
    #pragma unroll
    for (int s = 16; s >= 1; s >>= 1) {
        #pragma unroll
        for (int j = 0; j < RPS; ++j) {
            dot[j] += __shfl_xor(dot[j], s, 64);
            ksq[j] += __shfl_xor(ksq[j], s, 64);
        }
    }

    // Epilogue: p, scaled V rows, plain (L2 write-back) stores.
    float myp = 0.0f;
    #pragma unroll
    for (int j = 0; j < RPS; ++j) {
        const bool a = (bits >> j) & 1u;
        const float kn_inv = 1.0f / fmaxf(sqrtf(ksq[j]), EPS);
        const float p = a ? __expf(fabsf(dot[j]) * inv_qn * kn_inv) : 0.0f;
        if (l32 == j) myp = p;
        f32x4 ov;
        ov[0] = p * vv[j][0]; ov[1] = p * vv[j][1];
        ov[2] = p * vv[j][2]; ov[3] = p * vv[j][3];
        *reinterpret_cast<f32x4*>(obase + j * D) = ov;
    }

    // One coalesced 16B p_attn store per half-wave.
    if (l32 < RPS)
        out[P_OFF + baseRow + slotBase + l32] = myp;
}

extern "C" void kernel_launch(void* const* d_in, const int* in_sizes, int n_in,
                              void* d_out, int out_size, void* d_ws, size_t ws_size,
                              hipStream_t stream) {
    const float* q   = (const float*)d_in[0];
    const float* key = (const float*)d_in[1];
    const float* val = (const float*)d_in[2];
    const int*   msk = (const int*)d_in[3];
    float* out = (float*)d_out;

    dim3 grid(BH * CHUNKS);  // 8192 blocks
    dim3 block(WAVES * 64);  // 256 threads
    cosattn_kernel<<<grid, block, 0, stream>>>(q, key, val, msk, out);
}

// Round 7
// 43.492 us; speedup vs baseline: 1.0923x; 1.0923x over previous
//
#include <hip/hip_runtime.h>
#include <math.h>

#define EPS 1e-8f

// Problem shape (fixed by setup_inputs)
constexpr int B = 8, H = 16, K = 2048, D = 128;
constexpr int BH = B * H;
constexpr int ROWS_PER_BLOCK = 64;               // fine-grained one-shot blocks
constexpr int CHUNKS = K / ROWS_PER_BLOCK;       // 32 blocks per (b,h)
constexpr int WAVES = 4;                         // 256 threads/block
constexpr int SLOTS = WAVES * 2;                 // 8 half-wave row-slots
constexpr int RPS = ROWS_PER_BLOCK / SLOTS;      // 8 rows per slot (contiguous)
constexpr size_t P_OFF = (size_t)BH * K * D;

typedef float f32x4 __attribute__((ext_vector_type(4)));

__global__ __launch_bounds__(256, 4) void cosattn_kernel(
    const float* __restrict__ q,      // [BH, D]
    const float* __restrict__ key,    // [BH, K, D]
    const float* __restrict__ value,  // [BH, K, D]
    const int*   __restrict__ mask,   // [B, K]
    float* __restrict__ out)          // [BH*K*D] ++ [BH*K]
{
    const int tid  = threadIdx.x;
    const int lane = tid & 63;
    const int half = lane >> 5;       // which row-slot of the wave's pair
    const int l32  = lane & 31;       // lane within 32-lane row group
    const int wave = tid >> 6;
    const int slot = wave * 2 + half; // 0..7

    const int bh    = blockIdx.x / CHUNKS;
    const int chunk = blockIdx.x & (CHUNKS - 1);
    const int b     = bh / H;

    // This slot owns RPS contiguous rows.
    const int slotBase = chunk * ROWS_PER_BLOCK + slot * RPS;
    const size_t baseRow = (size_t)bh * K;

    // Mask bitmap: lanes 0..7 of each half-wave load this slot's masks.
    int mk = 0;
    if (l32 < RPS)
        mk = mask[b * K + slotBase + l32];
    const unsigned long long bal = __ballot(mk != 0);
    const unsigned bits = (unsigned)(bal >> (half * 32)) & 0xFFu;

    // Per-lane query fragment (both halves identical).
    const f32x4 qv = *reinterpret_cast<const f32x4*>(q + (size_t)bh * D + l32 * 4);

    const float* kbase = key   + (baseRow + slotBase) * D + l32 * 4;
    const float* vbase = value + (baseRow + slotBase) * D + l32 * 4;
    float*       obase = out   + (baseRow + slotBase) * D + l32 * 4;

    // Issue all K loads, then all V loads (16 independent loads in flight;
    // dot/ksq compute can start once the K half has returned).
    f32x4 kv[RPS], vv[RPS];
    #pragma unroll
    for (int j = 0; j < RPS; ++j)
        kv[j] = ((bits >> j) & 1u) ? *reinterpret_cast<const f32x4*>(kbase + j * D)
                                   : (f32x4)(0.0f);
    #pragma unroll
    for (int j = 0; j < RPS; ++j)
        vv[j] = ((bits >> j) & 1u) ? *reinterpret_cast<const f32x4*>(vbase + j * D)
                                   : (f32x4)(0.0f);

    // q-norm reduction (5 shuffle steps, stays within each 32-lane half).
    float qsq = qv[0]*qv[0] + qv[1]*qv[1] + qv[2]*qv[2] + qv[3]*qv[3];
    #pragma unroll
    for (int s = 16; s >= 1; s >>= 1)
        qsq += __shfl_xor(qsq, s, 64);
    const float inv_qn = 1.0f / fmaxf(sqrtf(qsq), EPS);

    // Interleaved butterfly reductions for the 8 rows (needs only K data).
    float dot[RPS], ksq[RPS];
    #pragma unroll
    for (int j = 0; j < RPS; ++j) {
        dot[j] = qv[0]*kv[j][0] + qv[1]*kv[j][1] + qv[2]*kv[j][2] + qv[3]*kv[j][3];
        ksq[j] = kv[j][0]*kv[j][0] + kv[j][1]*kv[j][1] + kv[j][2]*kv[j][2] + kv[j][3]*kv[j][3];
    }
    #pragma unroll
    for (int s = 16; s >= 1; s >>= 1) {
        #pragma unroll
        for (int j = 0; j < RPS; ++j) {
            dot[j] += __shfl_xor(dot[j], s, 64);
            ksq[j] += __shfl_xor(ksq[j], s, 64);
        }
    }

    // Epilogue: p, scaled V rows, NT (no-allocate, coherent) stores.
    float myp = 0.0f;
    #pragma unroll
    for (int j = 0; j < RPS; ++j) {
        const bool a = (bits >> j) & 1u;
        const float kn_inv = 1.0f / fmaxf(sqrtf(ksq[j]), EPS);
        const float p = a ? __expf(fabsf(dot[j]) * inv_qn * kn_inv) : 0.0f;
        if (l32 == j) myp = p;
        f32x4 ov;
        ov[0] = p * vv[j][0]; ov[1] = p * vv[j][1];
        ov[2] = p * vv[j][2]; ov[3] = p * vv[j][3];
        __builtin_nontemporal_store(ov, reinterpret_cast<f32x4*>(obase + j * D));
    }

    // One coalesced 32B p_attn store per half-wave.
    if (l32 < RPS)
        __builtin_nontemporal_store(myp, out + P_OFF + baseRow + slotBase + l32);
}

extern "C" void kernel_launch(void* const* d_in, const int* in_sizes, int n_in,
                              void* d_out, int out_size, void* d_ws, size_t ws_size,
                              hipStream_t stream) {
    const float* q   = (const float*)d_in[0];
    const float* key = (const float*)d_in[1];
    const float* val = (const float*)d_in[2];
    const int*   msk = (const int*)d_in[3];
    float* out = (float*)d_out;

    dim3 grid(BH * CHUNKS);  // 4096 blocks
    dim3 block(WAVES * 64);  // 256 threads
    cosattn_kernel<<<grid, block, 0, stream>>>(q, key, val, msk, out);
}

// Round 8
// 42.958 us; speedup vs baseline: 1.1059x; 1.0124x over previous
//
#include <hip/hip_runtime.h>
#include <math.h>

#define EPS 1e-8f

// FINAL: R4 structure (best measured: 43.1 us).
// Roofline evidence: FETCH 66.3 MB + WRITE 132.4 MB = 199 MB/dispatch at
// 4.6 TB/s effective = 73% of dense-copy ceiling; shortfall explained by
// Bernoulli(1/2) 512B holes in the read stream (DRAM page efficiency).
// Store policy A/B: nt no-allocate > plain write-back (+9%); sc0 sc1 bypass
// is incoherent with dirty-L2 memset lines (R5 correctness failure).
constexpr int B = 8, H = 16, K = 2048, D = 128;
constexpr int BH = B * H;
constexpr int ROWS_PER_BLOCK = 32;               // fine-grained one-shot blocks
constexpr int CHUNKS = K / ROWS_PER_BLOCK;       // 64 blocks per (b,h)
constexpr int WAVES = 4;                         // 256 threads/block
constexpr int SLOTS = WAVES * 2;                 // 8 half-wave row-slots
constexpr int RPS = ROWS_PER_BLOCK / SLOTS;      // 4 rows per slot (contiguous)
constexpr size_t P_OFF = (size_t)BH * K * D;

typedef float f32x4 __attribute__((ext_vector_type(4)));

__global__ __launch_bounds__(256) void cosattn_kernel(
    const float* __restrict__ q,      // [BH, D]
    const float* __restrict__ key,    // [BH, K, D]
    const float* __restrict__ value,  // [BH, K, D]
    const int*   __restrict__ mask,   // [B, K]
    float* __restrict__ out)          // [BH*K*D] ++ [BH*K]
{
    const int tid  = threadIdx.x;
    const int lane = tid & 63;
    const int half = lane >> 5;       // which row-slot of the wave's pair
    const int l32  = lane & 31;       // lane within 32-lane row group
    const int wave = tid >> 6;
    const int slot = wave * 2 + half; // 0..7

    const int bh    = blockIdx.x >> 6;        // / CHUNKS
    const int chunk = blockIdx.x & (CHUNKS - 1);
    const int b     = bh / H;

    // This slot owns RPS contiguous rows.
    const int slotBase = chunk * ROWS_PER_BLOCK + slot * RPS;
    const size_t baseRow = (size_t)bh * K;

    // Mask bitmap: lanes 0..3 of each half-wave load this slot's masks.
    int mk = 0;
    if (l32 < RPS)
        mk = mask[b * K + slotBase + l32];
    const unsigned long long bal = __ballot(mk != 0);
    const unsigned bits = (unsigned)(bal >> (half * 32)) & 0xFu;

    // Per-lane query fragment (both halves identical).
    const f32x4 qv = *reinterpret_cast<const f32x4*>(q + (size_t)bh * D + l32 * 4);

    const float* kbase = key   + (baseRow + slotBase) * D + l32 * 4;
    const float* vbase = value + (baseRow + slotBase) * D + l32 * 4;
    float*       obase = out   + (baseRow + slotBase) * D + l32 * 4;

    // Issue all K loads, then all V loads (K first: compute can start at vmcnt(4)).
    f32x4 kv[RPS], vv[RPS];
    #pragma unroll
    for (int j = 0; j < RPS; ++j)
        kv[j] = ((bits >> j) & 1u) ? *reinterpret_cast<const f32x4*>(kbase + j * D)
                                   : (f32x4)(0.0f);
    #pragma unroll
    for (int j = 0; j < RPS; ++j)
        vv[j] = ((bits >> j) & 1u) ? *reinterpret_cast<const f32x4*>(vbase + j * D)
                                   : (f32x4)(0.0f);

    // q-norm reduction (5 shuffle steps, stays within each 32-lane half).
    float qsq = qv[0]*qv[0] + qv[1]*qv[1] + qv[2]*qv[2] + qv[3]*qv[3];
    #pragma unroll
    for (int s = 16; s >= 1; s >>= 1)
        qsq += __shfl_xor(qsq, s, 64);
    const float inv_qn = 1.0f / fmaxf(sqrtf(qsq), EPS);

    // Interleaved butterfly reductions for the 4 rows (needs only K data).
    float dot[RPS], ksq[RPS];
    #pragma unroll
    for (int j = 0; j < RPS; ++j) {
        dot[j] = qv[0]*kv[j][0] + qv[1]*kv[j][1] + qv[2]*kv[j][2] + qv[3]*kv[j][3];
        ksq[j] = kv[j][0]*kv[j][0] + kv[j][1]*kv[j][1] + kv[j][2]*kv[j][2] + kv[j][3]*kv[j][3];
    }
    #pragma unroll
    for (int s = 16; s >= 1; s >>= 1) {
        #pragma unroll
        for (int j = 0; j < RPS; ++j) {
            dot[j] += __shfl_xor(dot[j], s, 64);
            ksq[j] += __shfl_xor(ksq[j], s, 64);
        }
    }

    // Epilogue: p, scaled V rows, NT (no-allocate, coherent) stores.
    float myp = 0.0f;
    #pragma unroll
    for (int j = 0; j < RPS; ++j) {
        const bool a = (bits >> j) & 1u;
        const float kn_inv = 1.0f / fmaxf(sqrtf(ksq[j]), EPS);
        const float p = a ? __expf(fabsf(dot[j]) * inv_qn * kn_inv) : 0.0f;
        if (l32 == j) myp = p;
        f32x4 ov;
        ov[0] = p * vv[j][0]; ov[1] = p * vv[j][1];
        ov[2] = p * vv[j][2]; ov[3] = p * vv[j][3];
        __builtin_nontemporal_store(ov, reinterpret_cast<f32x4*>(obase + j * D));
    }

    // One coalesced 16B p_attn store per half-wave.
    if (l32 < RPS)
        __builtin_nontemporal_store(myp, out + P_OFF + baseRow + slotBase + l32);
}

extern "C" void kernel_launch(void* const* d_in, const int* in_sizes, int n_in,
                              void* d_out, int out_size, void* d_ws, size_t ws_size,
                              hipStream_t stream) {
    const float* q   = (const float*)d_in[0];
    const float* key = (const float*)d_in[1];
    const float* val = (const float*)d_in[2];
    const int*   msk = (const int*)d_in[3];
    float* out = (float*)d_out;

    dim3 grid(BH * CHUNKS);  // 8192 blocks
    dim3 block(WAVES * 64);  // 256 threads
    cosattn_kernel<<<grid, block, 0, stream>>>(q, key, val, msk, out);
}